// Round 9
// baseline (407.210 us; speedup 1.0000x reference)
//
#include <hip/hip_runtime.h>
#include <hip/hip_fp16.h>
#include <hip/hip_cooperative_groups.h>
#include <math.h>

namespace cg = cooperative_groups;

// EdgeBiasAttention: B=2, N=20000, C=64, E=640000, H=16
// R9 vs R8: ALL prep (pack/zero, count, scan, fill) fused into one
// cooperative kernel with 3 grid.sync()s (was 5 dispatches; ~28us of
// inter-dispatch gaps measured). Scan = 20 block-local scans + serial
// atomic-flag chain (flags re-zeroed in phase A each call -> replay-safe).
// attn unchanged from R8 (near its L2-capacity gather floor).

#define EB_B 2
#define EB_C 64
#define EB_H 16

__device__ __forceinline__ unsigned f2h2(float a, float b) {
    __half2 h = __floats2half2_rn(a, b);
    return *reinterpret_cast<unsigned*>(&h);
}
__device__ __forceinline__ float2 h2f2(unsigned u) {
    __half2 h = *reinterpret_cast<__half2*>(&u);
    return __half22float2(h);
}

__global__ __launch_bounds__(256, 4) void eb_prep_coop(
    const float4* __restrict__ K4, const float4* __restrict__ V4,
    const int* __restrict__ dst, const int* __restrict__ src,
    const float2* __restrict__ efeat2,
    const float* __restrict__ W1, const float* __restrict__ b1,
    const float* __restrict__ W2, const float* __restrict__ b2,
    int* __restrict__ cnt, int* __restrict__ offsets,
    int* __restrict__ flags, int* __restrict__ slot,
    int2* __restrict__ ep, uint4* __restrict__ kv,
    int N, int E, int do_pack) {
    cg::grid_group grid = cg::this_grid();
    const int tid = blockIdx.x * blockDim.x + threadIdx.x;
    const int nthr = gridDim.x * blockDim.x;

    // ---- Phase A: pack K/V -> fp16 kv; zero cnt+flags; sentinel. ----
    if (do_pack) {
        const int total = EB_B * N * 16;
        for (int i = tid; i < total; i += nthr) {
            float4 k = K4[i], v = V4[i];
            uint4 o;
            o.x = f2h2(k.x, k.y); o.y = f2h2(k.z, k.w);
            o.z = f2h2(v.x, v.y); o.w = f2h2(v.z, v.w);
            kv[i] = o;
        }
    }
    for (int i = tid; i < N; i += nthr) cnt[i] = 0;
    if (tid < 32) flags[tid] = 0;
    if (tid == 0) offsets[N] = E;
    grid.sync();

    // ---- Phase B: histogram dst + per-edge slot. ----
    for (int e = tid; e < E; e += nthr)
        slot[e] = atomicAdd(&cnt[dst[e]], 1);
    grid.sync();

    // ---- Phase C: exclusive scan cnt -> offsets (1024/chunk, chain). ----
    const int NB = (N + 1023) >> 10;
    if ((int)blockIdx.x < NB) {
        __shared__ int wsum[4];
        __shared__ int s_agg, s_base;
        const int b = blockIdx.x, t = threadIdx.x;
        const int ln = t & 63, wv = t >> 6;
        const int i0 = (b << 10) + (t << 2);
        int e0 = (i0     < N) ? cnt[i0]     : 0;
        int e1 = (i0 + 1 < N) ? cnt[i0 + 1] : 0;
        int e2 = (i0 + 2 < N) ? cnt[i0 + 2] : 0;
        int e3 = (i0 + 3 < N) ? cnt[i0 + 3] : 0;
        int s0 = e0, s1 = s0 + e1, s2 = s1 + e2, s3 = s2 + e3;
        int x = s3;
#pragma unroll
        for (int off = 1; off < 64; off <<= 1) {
            int tv = __shfl_up(x, off, 64);
            if (ln >= off) x += tv;
        }
        if (ln == 63) wsum[wv] = x;
        __syncthreads();
        if (t == 0) {
            int c = 0;
#pragma unroll
            for (int j = 0; j < 4; ++j) { int tmp = wsum[j]; wsum[j] = c; c += tmp; }
            s_agg = c;
        }
        __syncthreads();
        const int excl0 = x - s3 + wsum[wv];   // block-local exclusive at i0
        if (t == 0) {
            int base = 0;
            if (b > 0) {
                while ((base = atomicAdd(&flags[b - 1], 0)) == 0) {}
                base -= 1;
            }
            atomicExch(&flags[b], base + s_agg + 1);
            s_base = base;
        }
        __syncthreads();
        const int B0 = s_base + excl0;
        if (i0     < N) offsets[i0]     = B0;
        if (i0 + 1 < N) offsets[i0 + 1] = B0 + s0;
        if (i0 + 2 < N) offsets[i0 + 2] = B0 + s1;
        if (i0 + 3 < N) offsets[i0 + 3] = B0 + s2;
    }
    grid.sync();

    // ---- Phase D: edge-bias MLP + atomic-free permuted scatter. ----
    for (int e = tid; e < E; e += nthr) {
        float2 ef = efeat2[e];
        float acc = b2[0];
#pragma unroll
        for (int h = 0; h < EB_H; ++h) {
            float a = fmaf(ef.x, W1[h], fmaf(ef.y, W1[EB_H + h], b1[h]));
            a = fmaxf(a, 0.0f);
            acc = fmaf(a, W2[h], acc);
        }
        ep[offsets[dst[e]] + slot[e]] = make_int2(src[e], __float_as_int(acc));
    }
}

// fp16 attn: one wave per (node,batch), BATCH-MAJOR; 4 groups x 16 lanes;
// group g takes edges start+it*8+g and +4 (one uint4 gather per edge).
__global__ __launch_bounds__(256) void eb_attn_fp16_kernel(
    const float4* __restrict__ Q4, const uint4* __restrict__ kv,
    const int2* __restrict__ ep, const int* __restrict__ offsets,
    float4* __restrict__ out4, int N) {
    int wave = threadIdx.x >> 6;
    int lane = threadIdx.x & 63;
    int task = blockIdx.x * 4 + wave;
    if (task >= N * EB_B) return;
    int b = (task >= N) ? 1 : 0;
    int n = task - (b ? N : 0);
    int g = lane >> 4;
    int cl = lane & 15;
    const size_t brow = (size_t)N * 16;
    float4 q = Q4[(size_t)b * brow + (size_t)n * 16 + cl];
    const uint4* kvb = kv + (size_t)b * brow;
    int start = offsets[n];
    int end = offsets[n + 1];
    int nit = (end - start + 7) >> 3;

    float m = -1e30f, s = 0.0f;
    float ax = 0.0f, ay = 0.0f, az = 0.0f, aw = 0.0f;

    for (int it = 0; it < nit; ++it) {
        int e0 = start + it * 8 + g;
        int e1 = e0 + 4;
        bool v0 = e0 < end;
        bool v1 = e1 < end;
        int2 md0 = ep[v0 ? e0 : 0];
        int2 md1 = ep[v1 ? e1 : 0];
        uint4 u0 = kvb[(size_t)md0.x * 16 + cl];
        uint4 u1 = kvb[(size_t)md1.x * 16 + cl];
        float2 k0a = h2f2(u0.x), k0b = h2f2(u0.y);
        float2 k1a = h2f2(u1.x), k1b = h2f2(u1.y);
        float p0 = fmaf(q.x, k0a.x, fmaf(q.y, k0a.y,
                   fmaf(q.z, k0b.x, q.w * k0b.y)));
        float p1 = fmaf(q.x, k1a.x, fmaf(q.y, k1a.y,
                   fmaf(q.z, k1b.x, q.w * k1b.y)));
        p0 += __shfl_xor(p0, 1);  p1 += __shfl_xor(p1, 1);
        p0 += __shfl_xor(p0, 2);  p1 += __shfl_xor(p1, 2);
        p0 += __shfl_xor(p0, 4);  p1 += __shfl_xor(p1, 4);
        p0 += __shfl_xor(p0, 8);  p1 += __shfl_xor(p1, 8);
        float l0 = v0 ? p0 + __int_as_float(md0.y) : -INFINITY;
        float l1 = v1 ? p1 + __int_as_float(md1.y) : -INFINITY;
        float mn = fmaxf(m, fmaxf(l0, l1));
        float sc = __expf(m - mn);
        float w0 = __expf(l0 - mn);
        float w1 = __expf(l1 - mn);
        float2 va0 = h2f2(u0.z), vb0 = h2f2(u0.w);
        float2 va1 = h2f2(u1.z), vb1 = h2f2(u1.w);
        s  = fmaf(s, sc, w0 + w1);
        ax = fmaf(ax, sc, fmaf(w0, va0.x, w1 * va1.x));
        ay = fmaf(ay, sc, fmaf(w0, va0.y, w1 * va1.y));
        az = fmaf(az, sc, fmaf(w0, vb0.x, w1 * vb1.x));
        aw = fmaf(aw, sc, fmaf(w0, vb0.y, w1 * vb1.y));
        m = mn;
    }

    float m1 = fmaxf(m, __shfl_xor(m, 16));
    float mA = fmaxf(m1, __shfl_xor(m1, 32));
    float scale = __expf(m - mA);
    s *= scale; ax *= scale; ay *= scale; az *= scale; aw *= scale;
    s  += __shfl_xor(s, 16);  s  += __shfl_xor(s, 32);
    ax += __shfl_xor(ax, 16); ax += __shfl_xor(ax, 32);
    ay += __shfl_xor(ay, 16); ay += __shfl_xor(ay, 32);
    az += __shfl_xor(az, 16); az += __shfl_xor(az, 32);
    aw += __shfl_xor(aw, 16); aw += __shfl_xor(aw, 32);

    if (lane < 16) {
        float inv = (end > start) ? 1.0f / s : 0.0f;
        float4 o;
        o.x = ax * inv; o.y = ay * inv; o.z = az * inv; o.w = aw * inv;
        out4[(size_t)b * brow + (size_t)n * 16 + cl] = o;
    }
}

// f32 fallback (only used if ws_size can't hold the kv copy).
__global__ __launch_bounds__(256) void eb_attn_f32_kernel(
    const float4* __restrict__ Q4, const float4* __restrict__ K4,
    const float4* __restrict__ V4,
    const int2* __restrict__ ep, const int* __restrict__ offsets,
    float4* __restrict__ out4, int N) {
    int wave = threadIdx.x >> 6;
    int lane = threadIdx.x & 63;
    int task = blockIdx.x * 4 + wave;
    if (task >= N * EB_B) return;
    int b = (task >= N) ? 1 : 0;
    int n = task - (b ? N : 0);
    int g = lane >> 4;
    int cl = lane & 15;
    const size_t brow = (size_t)N * 16;
    const float4* Qb = Q4 + (size_t)b * brow;
    const float4* Kb = K4 + (size_t)b * brow;
    const float4* Vb = V4 + (size_t)b * brow;
    float4 q = Qb[(size_t)n * 16 + cl];
    int start = offsets[n];
    int end = offsets[n + 1];
    int nit = (end - start + 3) >> 2;

    float m = -1e30f, s = 0.0f;
    float ax = 0.0f, ay = 0.0f, az = 0.0f, aw = 0.0f;
    for (int it = 0; it < nit; ++it) {
        int ei = start + it * 4 + g;
        bool valid = ei < end;
        int2 md = ep[valid ? ei : 0];
        int sv = md.x;
        float4 k = Kb[(size_t)sv * 16 + cl];
        float4 v = Vb[(size_t)sv * 16 + cl];
        float p = fmaf(q.x, k.x, fmaf(q.y, k.y, fmaf(q.z, k.z, q.w * k.w)));
        p += __shfl_xor(p, 1);
        p += __shfl_xor(p, 2);
        p += __shfl_xor(p, 4);
        p += __shfl_xor(p, 8);
        float l = valid ? p + __int_as_float(md.y) : -INFINITY;
        float mn = fmaxf(m, l);
        float sc = __expf(m - mn);
        float w  = __expf(l - mn);
        s  = fmaf(s, sc, w);
        ax = fmaf(ax, sc, w * v.x);
        ay = fmaf(ay, sc, w * v.y);
        az = fmaf(az, sc, w * v.z);
        aw = fmaf(aw, sc, w * v.w);
        m = mn;
    }
    float m1 = fmaxf(m, __shfl_xor(m, 16));
    float mA = fmaxf(m1, __shfl_xor(m1, 32));
    float scale = __expf(m - mA);
    s *= scale; ax *= scale; ay *= scale; az *= scale; aw *= scale;
    s  += __shfl_xor(s, 16);  s  += __shfl_xor(s, 32);
    ax += __shfl_xor(ax, 16); ax += __shfl_xor(ax, 32);
    ay += __shfl_xor(ay, 16); ay += __shfl_xor(ay, 32);
    az += __shfl_xor(az, 16); az += __shfl_xor(az, 32);
    aw += __shfl_xor(aw, 16); aw += __shfl_xor(aw, 32);
    if (lane < 16) {
        float inv = (end > start) ? 1.0f / s : 0.0f;
        float4 o;
        o.x = ax * inv; o.y = ay * inv; o.z = az * inv; o.w = aw * inv;
        out4[(size_t)b * brow + (size_t)n * 16 + cl] = o;
    }
}

extern "C" void kernel_launch(void* const* d_in, const int* in_sizes, int n_in,
                              void* d_out, int out_size, void* d_ws, size_t ws_size,
                              hipStream_t stream) {
    const float4* Q4    = (const float4*)d_in[0];
    const float4* K4    = (const float4*)d_in[1];
    const float4* V4    = (const float4*)d_in[2];
    const float2* ef2   = (const float2*)d_in[3];
    const float* W1     = (const float*)d_in[4];
    const float* b1     = (const float*)d_in[5];
    const float* W2     = (const float*)d_in[6];
    const float* b2     = (const float*)d_in[7];
    const int*   src    = (const int*)d_in[8];
    const int*   dst    = (const int*)d_in[9];
    float4* out4 = (float4*)d_out;

    int E = in_sizes[8];
    int N = in_sizes[0] / (EB_B * EB_C);

    // 16B-aligned ws layout.
    char* base = (char*)d_ws;
    size_t off = 0;
    auto take = [&](size_t nbytes) {
        char* p = base + off;
        off += (nbytes + 15) & ~(size_t)15;
        return p;
    };
    int* offsets = (int*)take((size_t)(N + 1) * 4);
    int* cnt     = (int*)take((size_t)N * 4);
    int* flags   = (int*)take(32 * 4);
    int* slot    = (int*)take((size_t)E * 4);
    int2* ep     = (int2*)take((size_t)E * 8);
    uint4* kv    = (uint4*)take((size_t)EB_B * N * 16 * sizeof(uint4));
    int do_pack = (off <= ws_size) ? 1 : 0;

    void* args[] = {
        (void*)&K4, (void*)&V4, (void*)&dst, (void*)&src, (void*)&ef2,
        (void*)&W1, (void*)&b1, (void*)&W2, (void*)&b2,
        (void*)&cnt, (void*)&offsets, (void*)&flags, (void*)&slot,
        (void*)&ep, (void*)&kv, (void*)&N, (void*)&E, (void*)&do_pack
    };
    hipLaunchCooperativeKernel((void*)eb_prep_coop, dim3(1024), dim3(256),
                               args, 0, stream);

    int tasks = N * EB_B;
    if (do_pack) {
        eb_attn_fp16_kernel<<<(tasks + 3) / 4, 256, 0, stream>>>(
            Q4, kv, ep, offsets, out4, N);
    } else {
        eb_attn_f32_kernel<<<(tasks + 3) / 4, 256, 0, stream>>>(
            Q4, K4, V4, ep, offsets, out4, N);
    }
}

// Round 10
// 128.971 us; speedup vs baseline: 3.1574x; 3.1574x over previous
//
#include <hip/hip_runtime.h>
#include <hip/hip_fp16.h>
#include <math.h>

// EdgeBiasAttention: B=2, N=20000, C=64, E=640000, H=16
// R10: revert coop (grid.sync ~100us each on gfx950 — R9 lesson).
// Structure: pack(+zero) -> count -> chained-scan -> fill -> attnK -> attnV.
// attn split: K-pass (logits+m,s; K fp16 2.56MB/batch -> XCD-L2-resident)
// then V-pass (w=exp(l-m), acc w*V; V fp16 2.56MB/batch -> L2-resident).
// Falls back to R8's proven single-pass interleaved-kv kernel if ws is small.

#define EB_B 2
#define EB_C 64
#define EB_H 16

__device__ __forceinline__ unsigned f2h2(float a, float b) {
    __half2 h = __floats2half2_rn(a, b);
    return *reinterpret_cast<unsigned*>(&h);
}
__device__ __forceinline__ float2 h2f2(unsigned u) {
    __half2 h = *reinterpret_cast<__half2*>(&u);
    return __half22float2(h);
}

// Pack K,V f32 -> fp16. mode 1: separate kpk/vpk (uint2 = 4ch each).
// mode 0: interleaved kv uint4 (R8 layout). Also zeroes cnt and flags.
__global__ __launch_bounds__(256) void eb_pack(
    const float4* __restrict__ K4, const float4* __restrict__ V4,
    uint2* __restrict__ kpk, uint2* __restrict__ vpk,
    uint4* __restrict__ kv, int total,
    int* __restrict__ cnt, int* __restrict__ flags, int N, int mode) {
    int i = blockIdx.x * blockDim.x + threadIdx.x;
    if (i < N) cnt[i] = 0;
    if (i < 32) flags[i] = 0;
    if (i >= total) return;
    float4 k = K4[i];
    float4 v = V4[i];
    if (mode) {
        kpk[i] = make_uint2(f2h2(k.x, k.y), f2h2(k.z, k.w));
        vpk[i] = make_uint2(f2h2(v.x, v.y), f2h2(v.z, v.w));
    } else {
        uint4 o;
        o.x = f2h2(k.x, k.y); o.y = f2h2(k.z, k.w);
        o.z = f2h2(v.x, v.y); o.w = f2h2(v.z, v.w);
        kv[i] = o;
    }
}

// Histogram dst + per-edge slot.
__global__ void eb_count_kernel(const int* __restrict__ dst,
                                int* __restrict__ cnt,
                                int* __restrict__ slot, int E) {
    int e = blockIdx.x * blockDim.x + threadIdx.x;
    if (e < E) slot[e] = atomicAdd(&cnt[dst[e]], 1);
}

// Single-kernel chained exclusive scan (NB<=32 blocks, flag chain).
__global__ __launch_bounds__(1024) void eb_scan(const int* __restrict__ cnt,
                                                int* __restrict__ offsets,
                                                int* __restrict__ flags,
                                                int N, int E) {
    __shared__ int wsum[16];
    __shared__ int s_agg, s_base;
    const int b = blockIdx.x, t = threadIdx.x;
    const int ln = t & 63, wv = t >> 6;
    const int i = (b << 10) + t;
    int v = (i < N) ? cnt[i] : 0;
    int x = v;
#pragma unroll
    for (int off = 1; off < 64; off <<= 1) {
        int tv = __shfl_up(x, off, 64);
        if (ln >= off) x += tv;
    }
    if (ln == 63) wsum[wv] = x;
    __syncthreads();
    if (wv == 0 && ln < 16) {
        int y = wsum[ln];
#pragma unroll
        for (int off = 1; off < 16; off <<= 1) {
            int tv = __shfl_up(y, off, 64);
            if (ln >= off) y += tv;
        }
        wsum[ln] = y;
    }
    __syncthreads();
    if (t == 1023) s_agg = wsum[15];
    __syncthreads();
    if (t == 0) {
        int base = 0;
        if (b > 0) {
            while ((base = atomicAdd(&flags[b - 1], 0)) == 0) {}
            base -= 1;
        }
        atomicExch(&flags[b], base + s_agg + 1);
        s_base = base;
    }
    __syncthreads();
    int local_excl = (wv > 0 ? wsum[wv - 1] : 0) + x - v;
    if (i < N) offsets[i] = s_base + local_excl;
    else if (i == N) offsets[N] = E;
}

// Edge-bias MLP + atomic-free permuted scatter of int2(src, f32 bias).
__global__ void eb_fill_kernel(const int* __restrict__ dst,
                               const int* __restrict__ src,
                               const int* __restrict__ slot,
                               const int* __restrict__ offsets,
                               const float2* __restrict__ efeat2,
                               const float* __restrict__ W1,
                               const float* __restrict__ b1,
                               const float* __restrict__ W2,
                               const float* __restrict__ b2,
                               int2* __restrict__ ep, int E) {
    int e = blockIdx.x * blockDim.x + threadIdx.x;
    if (e >= E) return;
    float2 ef = efeat2[e];
    float acc = b2[0];
#pragma unroll
    for (int h = 0; h < EB_H; ++h) {
        float a = fmaf(ef.x, W1[h], fmaf(ef.y, W1[EB_H + h], b1[h]));
        a = fmaxf(a, 0.0f);
        acc = fmaf(a, W2[h], acc);
    }
    int pos = offsets[dst[e]] + slot[e];
    ep[pos] = make_int2(src[e], __float_as_int(acc));
}

// Pass A: K-gather, logits -> ws, online (m,s) -> ms. Batch-major tasks.
__global__ __launch_bounds__(256) void eb_attn_k(
    const float4* __restrict__ Q4, const uint2* __restrict__ kpk,
    const int2* __restrict__ ep, const int* __restrict__ offsets,
    float* __restrict__ logits, float2* __restrict__ ms, int N, int E) {
    int wave = threadIdx.x >> 6;
    int lane = threadIdx.x & 63;
    int task = blockIdx.x * 4 + wave;
    if (task >= N * EB_B) return;
    int b = (task >= N) ? 1 : 0;
    int n = task - (b ? N : 0);
    int g = lane >> 4;
    int cl = lane & 15;
    float4 q = Q4[((size_t)b * N + n) * 16 + cl];
    const uint2* kb = kpk + (size_t)b * N * 16;
    float* lgb = logits + (size_t)b * E;
    int start = offsets[n];
    int end = offsets[n + 1];
    int nit = (end - start + 7) >> 3;

    float m = -1e30f, s = 0.0f;
    for (int it = 0; it < nit; ++it) {
        int e0 = start + it * 8 + g;
        int e1 = e0 + 4;
        bool v0 = e0 < end;
        bool v1 = e1 < end;
        int2 md0 = ep[v0 ? e0 : 0];
        int2 md1 = ep[v1 ? e1 : 0];
        uint2 u0 = kb[(size_t)md0.x * 16 + cl];
        uint2 u1 = kb[(size_t)md1.x * 16 + cl];
        float2 a0 = h2f2(u0.x), b0 = h2f2(u0.y);
        float2 a1 = h2f2(u1.x), b1_ = h2f2(u1.y);
        float p0 = fmaf(q.x, a0.x, fmaf(q.y, a0.y, fmaf(q.z, b0.x, q.w * b0.y)));
        float p1 = fmaf(q.x, a1.x, fmaf(q.y, a1.y, fmaf(q.z, b1_.x, q.w * b1_.y)));
        p0 += __shfl_xor(p0, 1);  p1 += __shfl_xor(p1, 1);
        p0 += __shfl_xor(p0, 2);  p1 += __shfl_xor(p1, 2);
        p0 += __shfl_xor(p0, 4);  p1 += __shfl_xor(p1, 4);
        p0 += __shfl_xor(p0, 8);  p1 += __shfl_xor(p1, 8);
        float l0 = v0 ? p0 + __int_as_float(md0.y) : -INFINITY;
        float l1 = v1 ? p1 + __int_as_float(md1.y) : -INFINITY;
        if (cl == 0) {
            if (v0) lgb[e0] = l0;
            if (v1) lgb[e1] = l1;
        }
        float mn = fmaxf(m, fmaxf(l0, l1));
        float sc = __expf(m - mn);
        s = fmaf(s, sc, __expf(l0 - mn) + __expf(l1 - mn));
        m = mn;
    }
    // merge 4 group (m,s) states
    float m1 = fmaxf(m, __shfl_xor(m, 16));
    float mA = fmaxf(m1, __shfl_xor(m1, 32));
    s *= __expf(m - mA);
    s += __shfl_xor(s, 16);
    s += __shfl_xor(s, 32);
    if (lane == 0) ms[(size_t)b * N + n] = make_float2(mA, s);
}

// Pass B: read logits sequentially, V-gather, acc += exp(l-m)*V.
__global__ __launch_bounds__(256) void eb_attn_v(
    const uint2* __restrict__ vpk, const int2* __restrict__ ep,
    const int* __restrict__ offsets, const float* __restrict__ logits,
    const float2* __restrict__ ms, float4* __restrict__ out4, int N, int E) {
    int wave = threadIdx.x >> 6;
    int lane = threadIdx.x & 63;
    int task = blockIdx.x * 4 + wave;
    if (task >= N * EB_B) return;
    int b = (task >= N) ? 1 : 0;
    int n = task - (b ? N : 0);
    int g = lane >> 4;
    int cl = lane & 15;
    const uint2* vb = vpk + (size_t)b * N * 16;
    const float* lgb = logits + (size_t)b * E;
    int start = offsets[n];
    int end = offsets[n + 1];
    int nit = (end - start + 7) >> 3;
    float2 msv = ms[(size_t)b * N + n];
    float m = msv.x;

    float ax = 0.0f, ay = 0.0f, az = 0.0f, aw = 0.0f;
    for (int it = 0; it < nit; ++it) {
        int e0 = start + it * 8 + g;
        int e1 = e0 + 4;
        bool v0 = e0 < end;
        bool v1 = e1 < end;
        int2 md0 = ep[v0 ? e0 : 0];
        int2 md1 = ep[v1 ? e1 : 0];
        float l0 = lgb[v0 ? e0 : 0];
        float l1 = lgb[v1 ? e1 : 0];
        uint2 u0 = vb[(size_t)md0.x * 16 + cl];
        uint2 u1 = vb[(size_t)md1.x * 16 + cl];
        float w0 = v0 ? __expf(l0 - m) : 0.0f;
        float w1 = v1 ? __expf(l1 - m) : 0.0f;
        float2 a0 = h2f2(u0.x), b0 = h2f2(u0.y);
        float2 a1 = h2f2(u1.x), b1_ = h2f2(u1.y);
        ax = fmaf(w0, a0.x, fmaf(w1, a1.x, ax));
        ay = fmaf(w0, a0.y, fmaf(w1, a1.y, ay));
        az = fmaf(w0, b0.x, fmaf(w1, b1_.x, az));
        aw = fmaf(w0, b0.y, fmaf(w1, b1_.y, aw));
    }
    ax += __shfl_xor(ax, 16); ax += __shfl_xor(ax, 32);
    ay += __shfl_xor(ay, 16); ay += __shfl_xor(ay, 32);
    az += __shfl_xor(az, 16); az += __shfl_xor(az, 32);
    aw += __shfl_xor(aw, 16); aw += __shfl_xor(aw, 32);
    if (lane < 16) {
        float inv = (end > start) ? 1.0f / msv.y : 0.0f;
        float4 o;
        o.x = ax * inv; o.y = ay * inv; o.z = az * inv; o.w = aw * inv;
        out4[((size_t)b * N + n) * 16 + cl] = o;
    }
}

// R8 fallback: single-pass interleaved-kv fp16 attn (known-good, known-fit).
__global__ __launch_bounds__(256) void eb_attn_fp16_kernel(
    const float4* __restrict__ Q4, const uint4* __restrict__ kv,
    const int2* __restrict__ ep, const int* __restrict__ offsets,
    float4* __restrict__ out4, int N) {
    int wave = threadIdx.x >> 6;
    int lane = threadIdx.x & 63;
    int task = blockIdx.x * 4 + wave;
    if (task >= N * EB_B) return;
    int b = (task >= N) ? 1 : 0;
    int n = task - (b ? N : 0);
    int g = lane >> 4;
    int cl = lane & 15;
    const size_t brow = (size_t)N * 16;
    float4 q = Q4[(size_t)b * brow + (size_t)n * 16 + cl];
    const uint4* kvb = kv + (size_t)b * brow;
    int start = offsets[n];
    int end = offsets[n + 1];
    int nit = (end - start + 7) >> 3;

    float m = -1e30f, s = 0.0f;
    float ax = 0.0f, ay = 0.0f, az = 0.0f, aw = 0.0f;
    for (int it = 0; it < nit; ++it) {
        int e0 = start + it * 8 + g;
        int e1 = e0 + 4;
        bool v0 = e0 < end;
        bool v1 = e1 < end;
        int2 md0 = ep[v0 ? e0 : 0];
        int2 md1 = ep[v1 ? e1 : 0];
        uint4 u0 = kvb[(size_t)md0.x * 16 + cl];
        uint4 u1 = kvb[(size_t)md1.x * 16 + cl];
        float2 k0a = h2f2(u0.x), k0b = h2f2(u0.y);
        float2 k1a = h2f2(u1.x), k1b = h2f2(u1.y);
        float p0 = fmaf(q.x, k0a.x, fmaf(q.y, k0a.y,
                   fmaf(q.z, k0b.x, q.w * k0b.y)));
        float p1 = fmaf(q.x, k1a.x, fmaf(q.y, k1a.y,
                   fmaf(q.z, k1b.x, q.w * k1b.y)));
        p0 += __shfl_xor(p0, 1);  p1 += __shfl_xor(p1, 1);
        p0 += __shfl_xor(p0, 2);  p1 += __shfl_xor(p1, 2);
        p0 += __shfl_xor(p0, 4);  p1 += __shfl_xor(p1, 4);
        p0 += __shfl_xor(p0, 8);  p1 += __shfl_xor(p1, 8);
        float l0 = v0 ? p0 + __int_as_float(md0.y) : -INFINITY;
        float l1 = v1 ? p1 + __int_as_float(md1.y) : -INFINITY;
        float mn = fmaxf(m, fmaxf(l0, l1));
        float sc = __expf(m - mn);
        float w0 = __expf(l0 - mn);
        float w1 = __expf(l1 - mn);
        float2 va0 = h2f2(u0.z), vb0 = h2f2(u0.w);
        float2 va1 = h2f2(u1.z), vb1 = h2f2(u1.w);
        s  = fmaf(s, sc, w0 + w1);
        ax = fmaf(ax, sc, fmaf(w0, va0.x, w1 * va1.x));
        ay = fmaf(ay, sc, fmaf(w0, va0.y, w1 * va1.y));
        az = fmaf(az, sc, fmaf(w0, vb0.x, w1 * vb1.x));
        aw = fmaf(aw, sc, fmaf(w0, vb0.y, w1 * vb1.y));
        m = mn;
    }
    float m1 = fmaxf(m, __shfl_xor(m, 16));
    float mA = fmaxf(m1, __shfl_xor(m1, 32));
    float scale = __expf(m - mA);
    s *= scale; ax *= scale; ay *= scale; az *= scale; aw *= scale;
    s  += __shfl_xor(s, 16);  s  += __shfl_xor(s, 32);
    ax += __shfl_xor(ax, 16); ax += __shfl_xor(ax, 32);
    ay += __shfl_xor(ay, 16); ay += __shfl_xor(ay, 32);
    az += __shfl_xor(az, 16); az += __shfl_xor(az, 32);
    aw += __shfl_xor(aw, 16); aw += __shfl_xor(aw, 32);
    if (lane < 16) {
        float inv = (end > start) ? 1.0f / s : 0.0f;
        float4 o;
        o.x = ax * inv; o.y = ay * inv; o.z = az * inv; o.w = aw * inv;
        out4[(size_t)b * brow + (size_t)n * 16 + cl] = o;
    }
}

extern "C" void kernel_launch(void* const* d_in, const int* in_sizes, int n_in,
                              void* d_out, int out_size, void* d_ws, size_t ws_size,
                              hipStream_t stream) {
    const float4* Q4  = (const float4*)d_in[0];
    const float4* K4  = (const float4*)d_in[1];
    const float4* V4  = (const float4*)d_in[2];
    const float2* ef2 = (const float2*)d_in[3];
    const float* W1   = (const float*)d_in[4];
    const float* b1   = (const float*)d_in[5];
    const float* W2   = (const float*)d_in[6];
    const float* b2   = (const float*)d_in[7];
    const int*   src  = (const int*)d_in[8];
    const int*   dst  = (const int*)d_in[9];
    float4* out4 = (float4*)d_out;

    const int E = in_sizes[8];
    const int N = in_sizes[0] / (EB_B * EB_C);
    const int total = EB_B * N * 16;

    // 16B-aligned ws layout. Shared prefix, then split-path or kv-path region.
    char* base = (char*)d_ws;
    size_t off = 0;
    auto take = [&](size_t nbytes) {
        char* p = base + off;
        off += (nbytes + 15) & ~(size_t)15;
        return p;
    };
    int* offsets = (int*)take((size_t)(N + 1) * 4);
    int* cnt     = (int*)take((size_t)N * 4);
    int* flags   = (int*)take(32 * 4);
    int* slot    = (int*)take((size_t)E * 4);
    int2* ep     = (int2*)take((size_t)E * 8);
    size_t prefix = off;
    // split path
    float* logits = (float*)take((size_t)EB_B * E * 4);
    float2* ms    = (float2*)take((size_t)EB_B * N * 8);
    uint2* kpk    = (uint2*)take((size_t)total * 8);
    uint2* vpk    = (uint2*)take((size_t)total * 8);
    size_t split_bytes = off;
    // kv path (overlays split region)
    off = prefix;
    uint4* kv = (uint4*)take((size_t)total * 16);
    size_t kv_bytes = off;

    int mode = (split_bytes <= ws_size) ? 1 : 0;   // kv path known to fit (R8)
    (void)kv_bytes;

    int tpb = 256;
    int NB = (N + 1023) >> 10;
    eb_pack<<<(total + tpb - 1) / tpb, tpb, 0, stream>>>(
        K4, V4, kpk, vpk, kv, total, cnt, flags, N, mode);
    eb_count_kernel<<<(E + tpb - 1) / tpb, tpb, 0, stream>>>(dst, cnt, slot, E);
    eb_scan<<<NB, 1024, 0, stream>>>(cnt, offsets, flags, N, E);
    eb_fill_kernel<<<(E + tpb - 1) / tpb, tpb, 0, stream>>>(
        dst, src, slot, offsets, ef2, W1, b1, W2, b2, ep, E);

    int tasks = N * EB_B;
    int blks = (tasks + 3) / 4;
    if (mode) {
        eb_attn_k<<<blks, tpb, 0, stream>>>(Q4, kpk, ep, offsets, logits, ms, N, E);
        eb_attn_v<<<blks, tpb, 0, stream>>>(vpk, ep, offsets, logits, ms, out4, N, E);
    } else {
        eb_attn_fp16_kernel<<<blks, tpb, 0, stream>>>(Q4, kv, ep, offsets, out4, N);
    }
}

// Round 11
// 104.232 us; speedup vs baseline: 3.9068x; 1.2374x over previous
//
#include <hip/hip_runtime.h>
#include <hip/hip_fp16.h>
#include <math.h>

// EdgeBiasAttention: B=2, N=20000, C=64, E=640000, H=16
// R11 = R8 structure (single-pass interleaved fp16 kv attn) +
//   - R10's single-kernel chained scan (5 dispatches total)
//   - attn: software-pipelined loop (md 2 ahead, gathers 1 ahead) + fdot2
//   - count: 4 edges/thread (int4 loads, more MLP)
// R9 lesson: no grid.sync on gfx950 (~100us each). R10 lesson: attn is
// latency/issue-bound, not fetch-BW-bound -> attack the chain, not bytes.

#define EB_B 2
#define EB_C 64
#define EB_H 16

typedef _Float16 h2v __attribute__((ext_vector_type(2)));

__device__ __forceinline__ unsigned f2h2(float a, float b) {
    __half2 h = __floats2half2_rn(a, b);
    return *reinterpret_cast<unsigned*>(&h);
}
__device__ __forceinline__ float2 h2f2(unsigned u) {
    __half2 h = *reinterpret_cast<__half2*>(&u);
    return __half22float2(h);
}
__device__ __forceinline__ h2v bch2(unsigned u) {
    h2v r;
    __builtin_memcpy(&r, &u, 4);
    return r;
}

// Pack K,V f32 -> interleaved fp16 kv (uint4 = K-quad + V-quad);
// also zeroes cnt and flags.
__global__ __launch_bounds__(256) void eb_pack(
    const float4* __restrict__ K4, const float4* __restrict__ V4,
    uint4* __restrict__ kv, int total,
    int* __restrict__ cnt, int* __restrict__ flags, int N) {
    int i = blockIdx.x * blockDim.x + threadIdx.x;
    if (i < N) cnt[i] = 0;
    if (i < 32) flags[i] = 0;
    if (i >= total) return;
    float4 k = K4[i];
    float4 v = V4[i];
    uint4 o;
    o.x = f2h2(k.x, k.y); o.y = f2h2(k.z, k.w);
    o.z = f2h2(v.x, v.y); o.w = f2h2(v.z, v.w);
    kv[i] = o;
}

// Histogram dst + per-edge slot, 4 edges/thread.
__global__ void eb_count4(const int4* __restrict__ dst4,
                          int* __restrict__ cnt,
                          int4* __restrict__ slot4, int E4) {
    int i = blockIdx.x * blockDim.x + threadIdx.x;
    if (i >= E4) return;
    int4 d = dst4[i];
    int4 s;
    s.x = atomicAdd(&cnt[d.x], 1);
    s.y = atomicAdd(&cnt[d.y], 1);
    s.z = atomicAdd(&cnt[d.z], 1);
    s.w = atomicAdd(&cnt[d.w], 1);
    slot4[i] = s;
}
__global__ void eb_count1(const int* __restrict__ dst,
                          int* __restrict__ cnt,
                          int* __restrict__ slot, int lo, int E) {
    int e = lo + blockIdx.x * blockDim.x + threadIdx.x;
    if (e < E) slot[e] = atomicAdd(&cnt[dst[e]], 1);
}

// Single-kernel chained exclusive scan (flag chain, no grid.sync).
__global__ __launch_bounds__(1024) void eb_scan(const int* __restrict__ cnt,
                                                int* __restrict__ offsets,
                                                int* __restrict__ flags,
                                                int N, int E) {
    __shared__ int wsum[16];
    __shared__ int s_agg, s_base;
    const int b = blockIdx.x, t = threadIdx.x;
    const int ln = t & 63, wv = t >> 6;
    const int i = (b << 10) + t;
    int v = (i < N) ? cnt[i] : 0;
    int x = v;
#pragma unroll
    for (int off = 1; off < 64; off <<= 1) {
        int tv = __shfl_up(x, off, 64);
        if (ln >= off) x += tv;
    }
    if (ln == 63) wsum[wv] = x;
    __syncthreads();
    if (wv == 0 && ln < 16) {
        int y = wsum[ln];
#pragma unroll
        for (int off = 1; off < 16; off <<= 1) {
            int tv = __shfl_up(y, off, 64);
            if (ln >= off) y += tv;
        }
        wsum[ln] = y;
    }
    __syncthreads();
    if (t == 1023) s_agg = wsum[15];
    __syncthreads();
    if (t == 0) {
        int base = 0;
        if (b > 0) {
            while ((base = atomicAdd(&flags[b - 1], 0)) == 0) {}
            base -= 1;
        }
        atomicExch(&flags[b], base + s_agg + 1);
        s_base = base;
    }
    __syncthreads();
    int local_excl = (wv > 0 ? wsum[wv - 1] : 0) + x - v;
    if (i < N) offsets[i] = s_base + local_excl;
    else if (i == N) offsets[N] = E;
}

// Edge-bias MLP + atomic-free permuted scatter of int2(src, f32 bias).
__global__ void eb_fill_kernel(const int* __restrict__ dst,
                               const int* __restrict__ src,
                               const int* __restrict__ slot,
                               const int* __restrict__ offsets,
                               const float2* __restrict__ efeat2,
                               const float* __restrict__ W1,
                               const float* __restrict__ b1,
                               const float* __restrict__ W2,
                               const float* __restrict__ b2,
                               int2* __restrict__ ep, int E) {
    int e = blockIdx.x * blockDim.x + threadIdx.x;
    if (e >= E) return;
    float2 ef = efeat2[e];
    float acc = b2[0];
#pragma unroll
    for (int h = 0; h < EB_H; ++h) {
        float a = fmaf(ef.x, W1[h], fmaf(ef.y, W1[EB_H + h], b1[h]));
        a = fmaxf(a, 0.0f);
        acc = fmaf(a, W2[h], acc);
    }
    int pos = offsets[dst[e]] + slot[e];
    ep[pos] = make_int2(src[e], __float_as_int(acc));
}

// Single-pass fp16 attn, batch-major, 4x16-lane groups, 2 edges/group/iter,
// software-pipelined: md loaded 2 iters ahead, gathers issued 1 iter ahead.
__global__ __launch_bounds__(256) void eb_attn_fp16(
    const float4* __restrict__ Q4, const uint4* __restrict__ kv,
    const int2* __restrict__ ep, const int* __restrict__ offsets,
    float4* __restrict__ out4, int N) {
    int wave = threadIdx.x >> 6;
    int lane = threadIdx.x & 63;
    int task = blockIdx.x * 4 + wave;
    if (task >= N * EB_B) return;
    int b = (task >= N) ? 1 : 0;
    int n = task - (b ? N : 0);
    int g = lane >> 4;
    int cl = lane & 15;
    const size_t brow = (size_t)N * 16;
    float4 qf = Q4[(size_t)b * brow + (size_t)n * 16 + cl];
    h2v q01; q01[0] = (_Float16)qf.x; q01[1] = (_Float16)qf.y;
    h2v q23; q23[0] = (_Float16)qf.z; q23[1] = (_Float16)qf.w;
    const uint4* kvb = kv + (size_t)b * brow;
    int start = offsets[n];
    int end = offsets[n + 1];
    int nit = (end - start + 7) >> 3;

    // prologue: md+gather for it=0, md for it=1
    int eP = start + g;
    int2 c0 = ep[eP < end ? eP : 0];
    int2 c1 = ep[eP + 4 < end ? eP + 4 : 0];
    uint4 u0 = kvb[(size_t)c0.x * 16 + cl];
    uint4 u1 = kvb[(size_t)c1.x * 16 + cl];
    int eN = start + 8 + g;
    int2 n0 = ep[eN < end ? eN : 0];
    int2 n1 = ep[eN + 4 < end ? eN + 4 : 0];

    float m = -1e30f, s = 0.0f;
    float ax = 0.0f, ay = 0.0f, az = 0.0f, aw = 0.0f;

    for (int it = 0; it < nit; ++it) {
        // issue next-iter gathers (from md loaded last iter)
        uint4 fu0 = kvb[(size_t)n0.x * 16 + cl];
        uint4 fu1 = kvb[(size_t)n1.x * 16 + cl];
        // load md for it+2 (sequential, safe-clamped)
        int e2 = start + (it + 2) * 8 + g;
        int2 nn0 = ep[e2 < end ? e2 : 0];
        int2 nn1 = ep[e2 + 4 < end ? e2 + 4 : 0];
        // compute current iter from u0/u1 (gathered one iter ago)
        int e0 = start + it * 8 + g;
        int e1 = e0 + 4;
        bool v0 = e0 < end;
        bool v1 = e1 < end;
        float p0 = __builtin_amdgcn_fdot2(q01, bch2(u0.x),
                   __builtin_amdgcn_fdot2(q23, bch2(u0.y), 0.0f, false), false);
        float p1 = __builtin_amdgcn_fdot2(q01, bch2(u1.x),
                   __builtin_amdgcn_fdot2(q23, bch2(u1.y), 0.0f, false), false);
        p0 += __shfl_xor(p0, 1);  p1 += __shfl_xor(p1, 1);
        p0 += __shfl_xor(p0, 2);  p1 += __shfl_xor(p1, 2);
        p0 += __shfl_xor(p0, 4);  p1 += __shfl_xor(p1, 4);
        p0 += __shfl_xor(p0, 8);  p1 += __shfl_xor(p1, 8);
        float l0 = v0 ? p0 + __int_as_float(c0.y) : -INFINITY;
        float l1 = v1 ? p1 + __int_as_float(c1.y) : -INFINITY;
        float mn = fmaxf(m, fmaxf(l0, l1));
        float sc = __expf(m - mn);
        float w0 = __expf(l0 - mn);
        float w1 = __expf(l1 - mn);
        float2 va0 = h2f2(u0.z), vb0 = h2f2(u0.w);
        float2 va1 = h2f2(u1.z), vb1 = h2f2(u1.w);
        s  = fmaf(s, sc, w0 + w1);
        ax = fmaf(ax, sc, fmaf(w0, va0.x, w1 * va1.x));
        ay = fmaf(ay, sc, fmaf(w0, va0.y, w1 * va1.y));
        az = fmaf(az, sc, fmaf(w0, vb0.x, w1 * vb1.x));
        aw = fmaf(aw, sc, fmaf(w0, vb0.y, w1 * vb1.y));
        m = mn;
        // rotate pipeline
        c0 = n0; c1 = n1; u0 = fu0; u1 = fu1; n0 = nn0; n1 = nn1;
    }

    float m1 = fmaxf(m, __shfl_xor(m, 16));
    float mA = fmaxf(m1, __shfl_xor(m1, 32));
    float scale = __expf(m - mA);
    s *= scale; ax *= scale; ay *= scale; az *= scale; aw *= scale;
    s  += __shfl_xor(s, 16);  s  += __shfl_xor(s, 32);
    ax += __shfl_xor(ax, 16); ax += __shfl_xor(ax, 32);
    ay += __shfl_xor(ay, 16); ay += __shfl_xor(ay, 32);
    az += __shfl_xor(az, 16); az += __shfl_xor(az, 32);
    aw += __shfl_xor(aw, 16); aw += __shfl_xor(aw, 32);

    if (lane < 16) {
        float inv = (end > start) ? 1.0f / s : 0.0f;
        float4 o;
        o.x = ax * inv; o.y = ay * inv; o.z = az * inv; o.w = aw * inv;
        out4[(size_t)b * brow + (size_t)n * 16 + cl] = o;
    }
}

// f32 fallback (only if ws can't hold kv; not expected on this harness).
__global__ __launch_bounds__(256) void eb_attn_f32(
    const float4* __restrict__ Q4, const float4* __restrict__ K4,
    const float4* __restrict__ V4,
    const int2* __restrict__ ep, const int* __restrict__ offsets,
    float4* __restrict__ out4, int N) {
    int wave = threadIdx.x >> 6;
    int lane = threadIdx.x & 63;
    int task = blockIdx.x * 4 + wave;
    if (task >= N * EB_B) return;
    int b = (task >= N) ? 1 : 0;
    int n = task - (b ? N : 0);
    int g = lane >> 4;
    int cl = lane & 15;
    const size_t brow = (size_t)N * 16;
    float4 q = Q4[(size_t)b * brow + (size_t)n * 16 + cl];
    const float4* Kb = K4 + (size_t)b * brow;
    const float4* Vb = V4 + (size_t)b * brow;
    int start = offsets[n];
    int end = offsets[n + 1];
    int nit = (end - start + 3) >> 2;
    float m = -1e30f, s = 0.0f;
    float ax = 0.0f, ay = 0.0f, az = 0.0f, aw = 0.0f;
    for (int it = 0; it < nit; ++it) {
        int ei = start + it * 4 + g;
        bool valid = ei < end;
        int2 md = ep[valid ? ei : 0];
        float4 k = Kb[(size_t)md.x * 16 + cl];
        float4 v = Vb[(size_t)md.x * 16 + cl];
        float p = fmaf(q.x, k.x, fmaf(q.y, k.y, fmaf(q.z, k.z, q.w * k.w)));
        p += __shfl_xor(p, 1);
        p += __shfl_xor(p, 2);
        p += __shfl_xor(p, 4);
        p += __shfl_xor(p, 8);
        float l = valid ? p + __int_as_float(md.y) : -INFINITY;
        float mn = fmaxf(m, l);
        float sc = __expf(m - mn);
        float w  = __expf(l - mn);
        s  = fmaf(s, sc, w);
        ax = fmaf(ax, sc, w * v.x);
        ay = fmaf(ay, sc, w * v.y);
        az = fmaf(az, sc, w * v.z);
        aw = fmaf(aw, sc, w * v.w);
        m = mn;
    }
    float m1 = fmaxf(m, __shfl_xor(m, 16));
    float mA = fmaxf(m1, __shfl_xor(m1, 32));
    float scale = __expf(m - mA);
    s *= scale; ax *= scale; ay *= scale; az *= scale; aw *= scale;
    s  += __shfl_xor(s, 16);  s  += __shfl_xor(s, 32);
    ax += __shfl_xor(ax, 16); ax += __shfl_xor(ax, 32);
    ay += __shfl_xor(ay, 16); ay += __shfl_xor(ay, 32);
    az += __shfl_xor(az, 16); az += __shfl_xor(az, 32);
    aw += __shfl_xor(aw, 16); aw += __shfl_xor(aw, 32);
    if (lane < 16) {
        float inv = (end > start) ? 1.0f / s : 0.0f;
        float4 o;
        o.x = ax * inv; o.y = ay * inv; o.z = az * inv; o.w = aw * inv;
        out4[(size_t)b * brow + (size_t)n * 16 + cl] = o;
    }
}

extern "C" void kernel_launch(void* const* d_in, const int* in_sizes, int n_in,
                              void* d_out, int out_size, void* d_ws, size_t ws_size,
                              hipStream_t stream) {
    const float4* Q4  = (const float4*)d_in[0];
    const float4* K4  = (const float4*)d_in[1];
    const float4* V4  = (const float4*)d_in[2];
    const float2* ef2 = (const float2*)d_in[3];
    const float* W1   = (const float*)d_in[4];
    const float* b1   = (const float*)d_in[5];
    const float* W2   = (const float*)d_in[6];
    const float* b2   = (const float*)d_in[7];
    const int*   src  = (const int*)d_in[8];
    const int*   dst  = (const int*)d_in[9];
    float4* out4 = (float4*)d_out;

    const int E = in_sizes[8];
    const int N = in_sizes[0] / (EB_B * EB_C);
    const int total = EB_B * N * 16;

    // 16B-aligned ws layout.
    char* base = (char*)d_ws;
    size_t off = 0;
    auto take = [&](size_t nbytes) {
        char* p = base + off;
        off += (nbytes + 15) & ~(size_t)15;
        return p;
    };
    int* offsets = (int*)take((size_t)(N + 1) * 4);
    int* cnt     = (int*)take((size_t)N * 4);
    int* flags   = (int*)take(32 * 4);
    int* slot    = (int*)take((size_t)E * 4);
    int2* ep     = (int2*)take((size_t)E * 8);
    uint4* kv    = (uint4*)take((size_t)total * 16);
    bool use_fp16 = off <= ws_size;

    const int tpb = 256;
    const int NB = (N + 1023) >> 10;
    eb_pack<<<(total + tpb - 1) / tpb, tpb, 0, stream>>>(
        K4, V4, kv, use_fp16 ? total : 0, cnt, flags, N);
    int E4 = E >> 2;
    if (E4 > 0)
        eb_count4<<<(E4 + tpb - 1) / tpb, tpb, 0, stream>>>(
            (const int4*)dst, cnt, (int4*)slot, E4);
    if (E & 3)
        eb_count1<<<1, 64, 0, stream>>>(dst, cnt, slot, E4 << 2, E);
    eb_scan<<<NB, 1024, 0, stream>>>(cnt, offsets, flags, N, E);
    eb_fill_kernel<<<(E + tpb - 1) / tpb, tpb, 0, stream>>>(
        dst, src, slot, offsets, ef2, W1, b1, W2, b2, ep, E);

    int tasks = N * EB_B;
    int blks = (tasks + 3) / 4;
    if (use_fp16) {
        eb_attn_fp16<<<blks, tpb, 0, stream>>>(Q4, kv, ep, offsets, out4, N);
    } else {
        eb_attn_f32<<<blks, tpb, 0, stream>>>(Q4, K4, V4, ep, offsets, out4, N);
    }
}

// Round 14
// 102.943 us; speedup vs baseline: 3.9557x; 1.0125x over previous
//
#include <hip/hip_runtime.h>
#include <hip/hip_fp16.h>
#include <math.h>

// EdgeBiasAttention: B=2, N=20000, C=64, E=640000, H=16
// R14 = R13 with the DPP ctrl made a template constant (builtin requires an
// immediate). Structure: pack -> count -> chained scan -> fill ->
// single-pass fp16 attn (pipelined, fdot2, DPP 16-lane reduce).
// Lessons: R9 no grid.sync; R10 attn latency-bound not BW; R11 serial
// returning atomics poison; R12 raw DPP asm breaks hazard insertion.

#define EB_B 2
#define EB_C 64
#define EB_H 16

typedef _Float16 h2v __attribute__((ext_vector_type(2)));

__device__ __forceinline__ unsigned f2h2(float a, float b) {
    __half2 h = __floats2half2_rn(a, b);
    return *reinterpret_cast<unsigned*>(&h);
}
__device__ __forceinline__ float2 h2f2(unsigned u) {
    __half2 h = *reinterpret_cast<__half2*>(&u);
    return __half22float2(h);
}
__device__ __forceinline__ h2v bch2(unsigned u) {
    h2v r;
    __builtin_memcpy(&r, &u, 4);
    return r;
}

// x += dpp_perm(x) via compiler-managed DPP (hazard-safe, ctrl immediate).
template <int CTRL>
__device__ __forceinline__ float dpp_add(float x) {
    int y = __builtin_amdgcn_update_dpp(0, __float_as_int(x), CTRL, 0xf, 0xf, true);
    return x + __int_as_float(y);
}
// All-reduce sum over each 16-lane row: quad xor1, xor2, ror4, ror8.
__device__ __forceinline__ float row16_allsum(float x) {
    x = dpp_add<0xB1>(x);    // quad_perm [1,0,3,2]
    x = dpp_add<0x4E>(x);    // quad_perm [2,3,0,1]
    x = dpp_add<0x124>(x);   // row_ror:4
    x = dpp_add<0x128>(x);   // row_ror:8
    return x;
}

// Pack K,V f32 -> interleaved fp16 kv (uint4 = K-quad + V-quad);
// also zeroes cnt and flags.
__global__ __launch_bounds__(256) void eb_pack(
    const float4* __restrict__ K4, const float4* __restrict__ V4,
    uint4* __restrict__ kv, int total,
    int* __restrict__ cnt, int* __restrict__ flags, int N) {
    int i = blockIdx.x * blockDim.x + threadIdx.x;
    if (i < N) cnt[i] = 0;
    if (i < 32) flags[i] = 0;
    if (i >= total) return;
    float4 k = K4[i];
    float4 v = V4[i];
    uint4 o;
    o.x = f2h2(k.x, k.y); o.y = f2h2(k.z, k.w);
    o.z = f2h2(v.x, v.y); o.w = f2h2(v.z, v.w);
    kv[i] = o;
}

// Histogram dst + per-edge slot (1 edge/thread; independent atomics).
__global__ void eb_count(const int* __restrict__ dst,
                         int* __restrict__ cnt,
                         int* __restrict__ slot, int E) {
    int e = blockIdx.x * blockDim.x + threadIdx.x;
    if (e < E) slot[e] = atomicAdd(&cnt[dst[e]], 1);
}

// Single-kernel chained exclusive scan (flag chain, no grid.sync).
__global__ __launch_bounds__(1024) void eb_scan(const int* __restrict__ cnt,
                                                int* __restrict__ offsets,
                                                int* __restrict__ flags,
                                                int N, int E) {
    __shared__ int wsum[16];
    __shared__ int s_agg, s_base;
    const int b = blockIdx.x, t = threadIdx.x;
    const int ln = t & 63, wv = t >> 6;
    const int i = (b << 10) + t;
    int v = (i < N) ? cnt[i] : 0;
    int x = v;
#pragma unroll
    for (int off = 1; off < 64; off <<= 1) {
        int tv = __shfl_up(x, off, 64);
        if (ln >= off) x += tv;
    }
    if (ln == 63) wsum[wv] = x;
    __syncthreads();
    if (wv == 0 && ln < 16) {
        int y = wsum[ln];
#pragma unroll
        for (int off = 1; off < 16; off <<= 1) {
            int tv = __shfl_up(y, off, 64);
            if (ln >= off) y += tv;
        }
        wsum[ln] = y;
    }
    __syncthreads();
    if (t == 1023) s_agg = wsum[15];
    __syncthreads();
    if (t == 0) {
        int base = 0;
        if (b > 0) {
            while ((base = atomicAdd(&flags[b - 1], 0)) == 0) {}
            base -= 1;
        }
        atomicExch(&flags[b], base + s_agg + 1);
        s_base = base;
    }
    __syncthreads();
    int local_excl = (wv > 0 ? wsum[wv - 1] : 0) + x - v;
    if (i < N) offsets[i] = s_base + local_excl;
    else if (i == N) offsets[N] = E;
}

// Edge-bias MLP + atomic-free permuted scatter of int2(src, f32 bias).
__global__ void eb_fill_kernel(const int* __restrict__ dst,
                               const int* __restrict__ src,
                               const int* __restrict__ slot,
                               const int* __restrict__ offsets,
                               const float2* __restrict__ efeat2,
                               const float* __restrict__ W1,
                               const float* __restrict__ b1,
                               const float* __restrict__ W2,
                               const float* __restrict__ b2,
                               int2* __restrict__ ep, int E) {
    int e = blockIdx.x * blockDim.x + threadIdx.x;
    if (e >= E) return;
    float2 ef = efeat2[e];
    float acc = b2[0];
#pragma unroll
    for (int h = 0; h < EB_H; ++h) {
        float a = fmaf(ef.x, W1[h], fmaf(ef.y, W1[EB_H + h], b1[h]));
        a = fmaxf(a, 0.0f);
        acc = fmaf(a, W2[h], acc);
    }
    int pos = offsets[dst[e]] + slot[e];
    ep[pos] = make_int2(src[e], __float_as_int(acc));
}

// Single-pass fp16 attn, batch-major, 4x16-lane groups, 2 edges/group/iter,
// software-pipelined (md 2 iters ahead, gathers 1 ahead), DPP dot-reduce.
__global__ __launch_bounds__(256) void eb_attn_fp16(
    const float4* __restrict__ Q4, const uint4* __restrict__ kv,
    const int2* __restrict__ ep, const int* __restrict__ offsets,
    float4* __restrict__ out4, int N) {
    int wave = threadIdx.x >> 6;
    int lane = threadIdx.x & 63;
    int task = blockIdx.x * 4 + wave;
    if (task >= N * EB_B) return;
    int b = (task >= N) ? 1 : 0;
    int n = task - (b ? N : 0);
    int g = lane >> 4;
    int cl = lane & 15;
    const size_t brow = (size_t)N * 16;
    float4 qf = Q4[(size_t)b * brow + (size_t)n * 16 + cl];
    h2v q01; q01[0] = (_Float16)qf.x; q01[1] = (_Float16)qf.y;
    h2v q23; q23[0] = (_Float16)qf.z; q23[1] = (_Float16)qf.w;
    const uint4* kvb = kv + (size_t)b * brow;
    int start = offsets[n];
    int end = offsets[n + 1];
    int nit = (end - start + 7) >> 3;

    // prologue: md+gather for it=0, md for it=1
    int eP = start + g;
    int2 c0 = ep[eP < end ? eP : 0];
    int2 c1 = ep[eP + 4 < end ? eP + 4 : 0];
    uint4 u0 = kvb[(size_t)c0.x * 16 + cl];
    uint4 u1 = kvb[(size_t)c1.x * 16 + cl];
    int eN = start + 8 + g;
    int2 n0 = ep[eN < end ? eN : 0];
    int2 n1 = ep[eN + 4 < end ? eN + 4 : 0];

    float m = -1e30f, s = 0.0f;
    float ax = 0.0f, ay = 0.0f, az = 0.0f, aw = 0.0f;

    for (int it = 0; it < nit; ++it) {
        // issue next-iter gathers (md was loaded last iter)
        uint4 fu0 = kvb[(size_t)n0.x * 16 + cl];
        uint4 fu1 = kvb[(size_t)n1.x * 16 + cl];
        // load md for it+2 (sequential, clamped)
        int e2 = start + (it + 2) * 8 + g;
        int2 nn0 = ep[e2 < end ? e2 : 0];
        int2 nn1 = ep[e2 + 4 < end ? e2 + 4 : 0];
        // compute current iter
        int e0 = start + it * 8 + g;
        int e1 = e0 + 4;
        bool v0 = e0 < end;
        bool v1 = e1 < end;
        float p0 = __builtin_amdgcn_fdot2(q01, bch2(u0.x),
                   __builtin_amdgcn_fdot2(q23, bch2(u0.y), 0.0f, false), false);
        float p1 = __builtin_amdgcn_fdot2(q01, bch2(u1.x),
                   __builtin_amdgcn_fdot2(q23, bch2(u1.y), 0.0f, false), false);
        p0 = row16_allsum(p0);
        p1 = row16_allsum(p1);
        float l0 = v0 ? p0 + __int_as_float(c0.y) : -INFINITY;
        float l1 = v1 ? p1 + __int_as_float(c1.y) : -INFINITY;
        float mn = fmaxf(fmaxf(m, l0), l1);
        float sc = __expf(m - mn);
        float w0 = __expf(l0 - mn);
        float w1 = __expf(l1 - mn);
        float2 va0 = h2f2(u0.z), vb0 = h2f2(u0.w);
        float2 va1 = h2f2(u1.z), vb1 = h2f2(u1.w);
        s  = fmaf(s, sc, w0 + w1);
        ax = fmaf(ax, sc, fmaf(w0, va0.x, w1 * va1.x));
        ay = fmaf(ay, sc, fmaf(w0, va0.y, w1 * va1.y));
        az = fmaf(az, sc, fmaf(w0, vb0.x, w1 * vb1.x));
        aw = fmaf(aw, sc, fmaf(w0, vb0.y, w1 * vb1.y));
        m = mn;
        // rotate pipeline
        c0 = n0; c1 = n1; u0 = fu0; u1 = fu1; n0 = nn0; n1 = nn1;
    }

    float m1 = fmaxf(m, __shfl_xor(m, 16));
    float mA = fmaxf(m1, __shfl_xor(m1, 32));
    float scale = __expf(m - mA);
    s *= scale; ax *= scale; ay *= scale; az *= scale; aw *= scale;
    s  += __shfl_xor(s, 16);  s  += __shfl_xor(s, 32);
    ax += __shfl_xor(ax, 16); ax += __shfl_xor(ax, 32);
    ay += __shfl_xor(ay, 16); ay += __shfl_xor(ay, 32);
    az += __shfl_xor(az, 16); az += __shfl_xor(az, 32);
    aw += __shfl_xor(aw, 16); aw += __shfl_xor(aw, 32);

    if (lane < 16) {
        float inv = (end > start) ? 1.0f / s : 0.0f;
        float4 o;
        o.x = ax * inv; o.y = ay * inv; o.z = az * inv; o.w = aw * inv;
        out4[(size_t)b * brow + (size_t)n * 16 + cl] = o;
    }
}

// f32 fallback (only if ws can't hold kv; not expected on this harness).
__global__ __launch_bounds__(256) void eb_attn_f32(
    const float4* __restrict__ Q4, const float4* __restrict__ K4,
    const float4* __restrict__ V4,
    const int2* __restrict__ ep, const int* __restrict__ offsets,
    float4* __restrict__ out4, int N) {
    int wave = threadIdx.x >> 6;
    int lane = threadIdx.x & 63;
    int task = blockIdx.x * 4 + wave;
    if (task >= N * EB_B) return;
    int b = (task >= N) ? 1 : 0;
    int n = task - (b ? N : 0);
    int g = lane >> 4;
    int cl = lane & 15;
    const size_t brow = (size_t)N * 16;
    float4 q = Q4[(size_t)b * brow + (size_t)n * 16 + cl];
    const float4* Kb = K4 + (size_t)b * brow;
    const float4* Vb = V4 + (size_t)b * brow;
    int start = offsets[n];
    int end = offsets[n + 1];
    int nit = (end - start + 3) >> 2;
    float m = -1e30f, s = 0.0f;
    float ax = 0.0f, ay = 0.0f, az = 0.0f, aw = 0.0f;
    for (int it = 0; it < nit; ++it) {
        int ei = start + it * 4 + g;
        bool valid = ei < end;
        int2 md = ep[valid ? ei : 0];
        float4 k = Kb[(size_t)md.x * 16 + cl];
        float4 v = Vb[(size_t)md.x * 16 + cl];
        float p = fmaf(q.x, k.x, fmaf(q.y, k.y, fmaf(q.z, k.z, q.w * k.w)));
        p = row16_allsum(p);
        float l = valid ? p + __int_as_float(md.y) : -INFINITY;
        float mn = fmaxf(m, l);
        float sc = __expf(m - mn);
        float w  = __expf(l - mn);
        s  = fmaf(s, sc, w);
        ax = fmaf(ax, sc, w * v.x);
        ay = fmaf(ay, sc, w * v.y);
        az = fmaf(az, sc, w * v.z);
        aw = fmaf(aw, sc, w * v.w);
        m = mn;
    }
    float m1 = fmaxf(m, __shfl_xor(m, 16));
    float mA = fmaxf(m1, __shfl_xor(m1, 32));
    float scale = __expf(m - mA);
    s *= scale; ax *= scale; ay *= scale; az *= scale; aw *= scale;
    s  += __shfl_xor(s, 16);  s  += __shfl_xor(s, 32);
    ax += __shfl_xor(ax, 16); ax += __shfl_xor(ax, 32);
    ay += __shfl_xor(ay, 16); ay += __shfl_xor(ay, 32);
    az += __shfl_xor(az, 16); az += __shfl_xor(az, 32);
    aw += __shfl_xor(aw, 16); aw += __shfl_xor(aw, 32);
    if (lane < 16) {
        float inv = (end > start) ? 1.0f / s : 0.0f;
        float4 o;
        o.x = ax * inv; o.y = ay * inv; o.z = az * inv; o.w = aw * inv;
        out4[(size_t)b * brow + (size_t)n * 16 + cl] = o;
    }
}

extern "C" void kernel_launch(void* const* d_in, const int* in_sizes, int n_in,
                              void* d_out, int out_size, void* d_ws, size_t ws_size,
                              hipStream_t stream) {
    const float4* Q4  = (const float4*)d_in[0];
    const float4* K4  = (const float4*)d_in[1];
    const float4* V4  = (const float4*)d_in[2];
    const float2* ef2 = (const float2*)d_in[3];
    const float* W1   = (const float*)d_in[4];
    const float* b1   = (const float*)d_in[5];
    const float* W2   = (const float*)d_in[6];
    const float* b2   = (const float*)d_in[7];
    const int*   src  = (const int*)d_in[8];
    const int*   dst  = (const int*)d_in[9];
    float4* out4 = (float4*)d_out;

    const int E = in_sizes[8];
    const int N = in_sizes[0] / (EB_B * EB_C);
    const int total = EB_B * N * 16;

    // 16B-aligned ws layout.
    char* base = (char*)d_ws;
    size_t off = 0;
    auto take = [&](size_t nbytes) {
        char* p = base + off;
        off += (nbytes + 15) & ~(size_t)15;
        return p;
    };
    int* offsets = (int*)take((size_t)(N + 1) * 4);
    int* cnt     = (int*)take((size_t)N * 4);
    int* flags   = (int*)take(32 * 4);
    int* slot    = (int*)take((size_t)E * 4);
    int2* ep     = (int2*)take((size_t)E * 8);
    uint4* kv    = (uint4*)take((size_t)total * 16);
    bool use_fp16 = off <= ws_size;

    const int tpb = 256;
    const int NB = (N + 1023) >> 10;
    eb_pack<<<(total + tpb - 1) / tpb, tpb, 0, stream>>>(
        K4, V4, kv, use_fp16 ? total : 0, cnt, flags, N);
    eb_count<<<(E + tpb - 1) / tpb, tpb, 0, stream>>>(dst, cnt, slot, E);
    eb_scan<<<NB, 1024, 0, stream>>>(cnt, offsets, flags, N, E);
    eb_fill_kernel<<<(E + tpb - 1) / tpb, tpb, 0, stream>>>(
        dst, src, slot, offsets, ef2, W1, b1, W2, b2, ep, E);

    int tasks = N * EB_B;
    int blks = (tasks + 3) / 4;
    if (use_fp16) {
        eb_attn_fp16<<<blks, tpb, 0, stream>>>(Q4, kv, ep, offsets, out4, N);
    } else {
        eb_attn_f32<<<blks, tpb, 0, stream>>>(Q4, K4, V4, ep, offsets, out4, N);
    }
}